// Round 11
// baseline (392.813 us; speedup 1.0000x reference)
//
#include <hip/hip_runtime.h>
#include <hip/hip_bf16.h>

typedef _Float16 half8 __attribute__((ext_vector_type(8)));
typedef _Float16 half4v __attribute__((ext_vector_type(4)));
typedef float floatx4 __attribute__((ext_vector_type(4)));
typedef float floatx16 __attribute__((ext_vector_type(16)));

// ---------------------------------------------------------------------------
// Swizzled LDS layouts (chunk = 8 halfs = 16B, rotated by row).
// act buffer: 128x256 fp16 (64 KiB, single, in-place read->barrier->write).
// x buffer: 128x64 fp16 (16 KiB). Total 81920 B -> exactly 2 blocks/CU.
// ---------------------------------------------------------------------------
__device__ __forceinline__ int swz(int row, int col) {
    return row * 256 + ((((col >> 3) + row) & 31) << 3) + (col & 7);
}
__device__ __forceinline__ int xswz(int row, int col) {
    return row * 64 + ((((col >> 3) + row) & 7) << 3) + (col & 7);
}

// ---------------------------------------------------------------------------
// Weight pre-pack (unchanged, numerically proven R5-R10): fp32 (K,N)
// row-major -> fp16 fragment order; lane L holds
// W[kt*16 + 8*(L>>5) + j][nt*32 + (L&31)]. Fed to the MFMA *A* operand so
// D = C^T. K zero-padded: L1 39->64 (KT=4), L5 295->320 (KT=20), others 256
// (KT=16). L9 N 4->32. Tile starts (1KB tiles):
// {0,32,160,288,416,576,704,832,960}, total 976 tiles = 999424 B in d_ws.
// ---------------------------------------------------------------------------
__global__ void pack_w32(const float* __restrict__ w1, const float* __restrict__ w2,
                         const float* __restrict__ w3, const float* __restrict__ w4,
                         const float* __restrict__ w5, const float* __restrict__ w6,
                         const float* __restrict__ w7, const float* __restrict__ w8,
                         const float* __restrict__ w9, _Float16* __restrict__ dst) {
    const int tileStart[10] = {0, 32, 160, 288, 416, 576, 704, 832, 960, 976};
    const int Ks[9] = {39, 256, 256, 256, 295, 256, 256, 256, 256};
    const int Ns[9] = {256, 256, 256, 256, 256, 256, 256, 256, 4};
    const int Tn[9] = {8, 8, 8, 8, 8, 8, 8, 8, 1};
    const float* ws[9] = {w1, w2, w3, w4, w5, w6, w7, w8, w9};

    int g = blockIdx.x * blockDim.x + threadIdx.x;
    int tile = g >> 6, lane = g & 63;
    if (tile >= 976) return;
    int layer = 0;
    while (tile >= tileStart[layer + 1]) layer++;
    int t = tile - tileStart[layer];
    int tn = Tn[layer];
    int kt = t / tn, nt = t - kt * tn;
    int k0 = kt * 16 + (lane >> 5) * 8;
    int n = nt * 32 + (lane & 31);
    const float* w = ws[layer];
    int K = Ks[layer], N = Ns[layer];
    _Float16 v[8];
#pragma unroll
    for (int j = 0; j < 8; j++) {
        int k = k0 + j;
        v[j] = (k < K && n < N) ? (_Float16)w[k * N + n] : (_Float16)0.f;
    }
    *(half8*)(dst + (size_t)tile * 512 + lane * 8) = *(half8*)v;
}

// Act-fragment read for k-step ks (rows mbase..mbase+31 -> a0, +32..63 -> a1);
// fed to the MFMA *B* operand. AMODE 0: act buffer. 1: ks>=KS0 from x buffer
// (layer-5 skip concat). 2: entirely from x buffer (layer 1).
template <int AMODE, int KS0>
__device__ __forceinline__ void loadA(const _Float16* abuf,
                                      const _Float16* __restrict__ xbuf,
                                      int ks, int mbase, int l31, int lhi,
                                      half8& a0, half8& a1) {
    if (AMODE == 2 || (AMODE == 1 && ks >= KS0)) {
        int c = ((AMODE == 2) ? ks : (ks - KS0)) * 16 + lhi * 8;
        a0 = *(const half8*)(xbuf + xswz(mbase + l31, c));
        a1 = *(const half8*)(xbuf + xswz(mbase + 32 + l31, c));
    } else {
        int c = ks * 16 + lhi * 8;
        a0 = *(const half8*)(abuf + swz(mbase + l31, c));
        a1 = *(const half8*)(abuf + swz(mbase + 32 + l31, c));
    }
}

// ---------------------------------------------------------------------------
// One fused layer: C(128x256) = relu(A(128xK) @ W + b), in-place LDS->LDS.
// R11 = R10's exact per-wave body (2m x 2n swapped-operand tile, depth-2 W
// ring, anti-hoist bias fence; 64 arch + 64 AGPR = fits (512,4)'s 128 cap)
// scaled to 128-row blocks with 8 waves: wave w -> n-pair (w&3), m-half
// (w>>2). Waves w and w+4 read IDENTICAL W fragment streams in lockstep ->
// L1 temporal hits halve per-CU L2 W-traffic (R10 measured ~14 TB/s
// aggregate = 40% of L2 ceiling, the prime latency-under-load suspect);
// per-row barrier count also halves.
// ---------------------------------------------------------------------------
template <int KT, int AMODE, int KS0>
__device__ __forceinline__ void layerT(const _Float16* abuf,
                                       const _Float16* __restrict__ xbuf,
                                       const half8* __restrict__ wq,
                                       const float* __restrict__ bias,
                                       _Float16* obuf,
                                       int lane, int npair, int mbase) {
    static_assert((KT & 1) == 0 && KT >= 4, "KT must be even >= 4");
    const int l31 = lane & 31, lhi = lane >> 5;
    // W frag (kstep ks, n-tile npair*2+n): wl[ks*512 + n*64]
    const half8* wl = wq + (npair * 2) * 64 + lane;
    floatx16 acc00 = {}, acc01 = {}, acc10 = {}, acc11 = {};  // [ni][mi]
    half8 wA0 = wl[0], wA1 = wl[64];
    half8 wB0 = wl[512], wB1 = wl[512 + 64];
#pragma unroll 1
    for (int ks = 0; ks < KT - 2; ks += 2) {
        half8 nA0 = wl[(ks + 2) * 512], nA1 = wl[(ks + 2) * 512 + 64];
        half8 nB0 = wl[(ks + 3) * 512], nB1 = wl[(ks + 3) * 512 + 64];
        half8 a0, a1;
        loadA<AMODE, KS0>(abuf, xbuf, ks, mbase, l31, lhi, a0, a1);
        acc00 = __builtin_amdgcn_mfma_f32_32x32x16_f16(wA0, a0, acc00, 0, 0, 0);
        acc10 = __builtin_amdgcn_mfma_f32_32x32x16_f16(wA1, a0, acc10, 0, 0, 0);
        acc01 = __builtin_amdgcn_mfma_f32_32x32x16_f16(wA0, a1, acc01, 0, 0, 0);
        acc11 = __builtin_amdgcn_mfma_f32_32x32x16_f16(wA1, a1, acc11, 0, 0, 0);
        loadA<AMODE, KS0>(abuf, xbuf, ks + 1, mbase, l31, lhi, a0, a1);
        acc00 = __builtin_amdgcn_mfma_f32_32x32x16_f16(wB0, a0, acc00, 0, 0, 0);
        acc10 = __builtin_amdgcn_mfma_f32_32x32x16_f16(wB1, a0, acc10, 0, 0, 0);
        acc01 = __builtin_amdgcn_mfma_f32_32x32x16_f16(wB0, a1, acc01, 0, 0, 0);
        acc11 = __builtin_amdgcn_mfma_f32_32x32x16_f16(wB1, a1, acc11, 0, 0, 0);
        wA0 = nA0; wA1 = nA1; wB0 = nB0; wB1 = nB1;
    }
    {   // tail: k-steps KT-2 (wA) and KT-1 (wB), already in the ring
        half8 a0, a1;
        loadA<AMODE, KS0>(abuf, xbuf, KT - 2, mbase, l31, lhi, a0, a1);
        acc00 = __builtin_amdgcn_mfma_f32_32x32x16_f16(wA0, a0, acc00, 0, 0, 0);
        acc10 = __builtin_amdgcn_mfma_f32_32x32x16_f16(wA1, a0, acc10, 0, 0, 0);
        acc01 = __builtin_amdgcn_mfma_f32_32x32x16_f16(wA0, a1, acc01, 0, 0, 0);
        acc11 = __builtin_amdgcn_mfma_f32_32x32x16_f16(wA1, a1, acc11, 0, 0, 0);
        loadA<AMODE, KS0>(abuf, xbuf, KT - 1, mbase, l31, lhi, a0, a1);
        acc00 = __builtin_amdgcn_mfma_f32_32x32x16_f16(wB0, a0, acc00, 0, 0, 0);
        acc10 = __builtin_amdgcn_mfma_f32_32x32x16_f16(wB1, a0, acc10, 0, 0, 0);
        acc01 = __builtin_amdgcn_mfma_f32_32x32x16_f16(wB0, a1, acc01, 0, 0, 0);
        acc11 = __builtin_amdgcn_mfma_f32_32x32x16_f16(wB1, a1, acc11, 0, 0, 0);
    }
    // In-place safety barrier: all waves' act-reads complete before any write.
    if (AMODE != 2) __syncthreads();
    // Anti-hoist fence: keep the 32 VGPRs of bias out of the k-loop live range.
    asm volatile("" ::: "memory");
    floatx4 bv[2][4];
#pragma unroll
    for (int ni = 0; ni < 2; ni++)
#pragma unroll
        for (int g = 0; g < 4; g++)
            bv[ni][g] = *(const floatx4*)(bias + npair * 64 + ni * 32 + lhi * 4 + g * 8);
    // Epilogue: bias + relu + fp16, 4-half vector writes. D=C^T layout:
    // row m = mbase + mi*32 + (lane&31), col n = npair*64 + ni*32 + lhi*4 + g*8 + r.
#pragma unroll
    for (int ni = 0; ni < 2; ni++) {
#pragma unroll
        for (int mi = 0; mi < 2; mi++) {
            const floatx16 accv = (ni == 0) ? (mi == 0 ? acc00 : acc01)
                                            : (mi == 0 ? acc10 : acc11);
            int row = mbase + mi * 32 + l31;
#pragma unroll
            for (int g = 0; g < 4; g++) {
                int col = npair * 64 + ni * 32 + lhi * 4 + g * 8;
                half4v h;
#pragma unroll
                for (int r = 0; r < 4; r++) {
                    float v = accv[g * 4 + r] + bv[ni][g][r];
                    v = v > 0.f ? v : 0.f;
                    h[r] = (_Float16)v;
                }
                *(half4v*)(obuf + swz(row, col)) = h;
            }
        }
    }
}

// Layer 9 (swapped): 256 -> 4 (N padded to 32). Waves 0-3 take one 32-row
// m-tile each (128 rows); D[n][m]: lanes 0..31 hold n=r (r<4) for row m=l31
// -> one float4 store per lane.
__device__ __forceinline__ void layer9T(const _Float16* abuf,
                                        const half8* __restrict__ wq,
                                        const float* __restrict__ b9,
                                        float* __restrict__ out, long r0,
                                        int lane, int wave) {
    if (wave >= 4) return;
    const int l31 = lane & 31, lhi = lane >> 5;
    floatx16 acc = {};
    const half8* wl = wq + lane;
    half8 wc = wl[0];
#pragma unroll 1
    for (int ks = 0; ks < 15; ks++) {
        half8 wn = wl[(ks + 1) * 64];
        half8 a = *(const half8*)(abuf + swz(wave * 32 + l31, ks * 16 + lhi * 8));
        acc = __builtin_amdgcn_mfma_f32_32x32x16_f16(wc, a, acc, 0, 0, 0);
        wc = wn;
    }
    {
        half8 a = *(const half8*)(abuf + swz(wave * 32 + l31, 15 * 16 + lhi * 8));
        acc = __builtin_amdgcn_mfma_f32_32x32x16_f16(wc, a, acc, 0, 0, 0);
    }
    if (lhi == 0) {
        asm volatile("" ::: "memory");
        floatx4 b4 = *(const floatx4*)(b9);
        floatx4 o;
#pragma unroll
        for (int r = 0; r < 4; r++) o[r] = acc[r] + b4[r];
        *(floatx4*)(out + (r0 + wave * 32 + l31) * 4) = o;
    }
}

__global__ __launch_bounds__(512, 4) void mlp_fused(
    const float* __restrict__ x, const _Float16* __restrict__ wpk,
    const float* __restrict__ b1, const float* __restrict__ b2,
    const float* __restrict__ b3, const float* __restrict__ b4,
    const float* __restrict__ b5, const float* __restrict__ b6,
    const float* __restrict__ b7, const float* __restrict__ b8,
    const float* __restrict__ b9, float* __restrict__ out) {
    // 64 KiB act buffer + 16 KiB x tile = 81920 B; 8-wave blocks;
    // 2 blocks/CU (exactly 160 KiB) = 16 waves/CU = 4 waves/SIMD at
    // <=128 total regs/wave (R10's body: 64 arch + 64 AGPR).
    __shared__ _Float16 lds[128 * 256 + 128 * 64];
    _Float16* buf = lds;
    _Float16* xbuf = lds + 128 * 256;
    const int tid = threadIdx.x;
    const int lane = tid & 63, wave = tid >> 6;
    const int npair = wave & 3;          // n-column pair (cols 64*npair..+63)
    const int mbase = (wave >> 2) * 64;  // m-half (rows mbase..mbase+63)
    const long r0 = (long)blockIdx.x * 128;

    // Stage x: zero pad cols (39..63) and fill cols 0..38 — disjoint, one barrier.
    for (int i = tid; i < 128 * 25; i += 512) {
        int row = i / 25, col = 39 + (i - row * 25);
        xbuf[xswz(row, col)] = (_Float16)0.f;
    }
    for (int i = tid; i < 128 * 39; i += 512) {
        int row = i / 39, col = i - row * 39;
        xbuf[xswz(row, col)] = (_Float16)x[r0 * 39 + i];  // contiguous 4992 floats
    }
    __syncthreads();

    const half8* wp = (const half8*)wpk;  // tile = 64 half8 (1 KB)
    const half8* w1q = wp + (size_t)0 * 64;
    const half8* w2q = wp + (size_t)32 * 64;
    const half8* w3q = wp + (size_t)160 * 64;
    const half8* w4q = wp + (size_t)288 * 64;
    const half8* w5q = wp + (size_t)416 * 64;
    const half8* w6q = wp + (size_t)576 * 64;
    const half8* w7q = wp + (size_t)704 * 64;
    const half8* w8q = wp + (size_t)832 * 64;
    const half8* w9q = wp + (size_t)960 * 64;

    layerT<4, 2, 0>(xbuf, xbuf, w1q, b1, buf, lane, npair, mbase);   // x -> buf
    __syncthreads();
    layerT<16, 0, 0>(buf, xbuf, w2q, b2, buf, lane, npair, mbase);
    __syncthreads();
    layerT<16, 0, 0>(buf, xbuf, w3q, b3, buf, lane, npair, mbase);
    __syncthreads();
    layerT<16, 0, 0>(buf, xbuf, w4q, b4, buf, lane, npair, mbase);
    __syncthreads();
    layerT<20, 1, 16>(buf, xbuf, w5q, b5, buf, lane, npair, mbase);  // [h|x] skip
    __syncthreads();
    layerT<16, 0, 0>(buf, xbuf, w6q, b6, buf, lane, npair, mbase);
    __syncthreads();
    layerT<16, 0, 0>(buf, xbuf, w7q, b7, buf, lane, npair, mbase);
    __syncthreads();
    layerT<16, 0, 0>(buf, xbuf, w8q, b8, buf, lane, npair, mbase);
    __syncthreads();
    layer9T(buf, w9q, b9, out, r0, lane, wave);
}

extern "C" void kernel_launch(void* const* d_in, const int* in_sizes, int n_in,
                              void* d_out, int out_size, void* d_ws, size_t ws_size,
                              hipStream_t stream) {
    const float* x = (const float*)d_in[0];
    const float* w[9];
    const float* b[9];
    for (int i = 0; i < 9; i++) {
        w[i] = (const float*)d_in[1 + 2 * i];
        b[i] = (const float*)d_in[2 + 2 * i];
    }
    _Float16* wpk = (_Float16*)d_ws;  // 999424 B

    pack_w32<<<244, 256, 0, stream>>>(w[0], w[1], w[2], w[3], w[4], w[5], w[6], w[7], w[8], wpk);
    mlp_fused<<<262144 / 128, 512, 0, stream>>>(x, wpk, b[0], b[1], b[2], b[3], b[4],
                                                b[5], b[6], b[7], b[8], (float*)d_out);
}

// Round 12
// 383.139 us; speedup vs baseline: 1.0252x; 1.0252x over previous
//
#include <hip/hip_runtime.h>
#include <hip/hip_bf16.h>

typedef _Float16 half8 __attribute__((ext_vector_type(8)));
typedef _Float16 half4v __attribute__((ext_vector_type(4)));
typedef float floatx4 __attribute__((ext_vector_type(4)));
typedef float floatx16 __attribute__((ext_vector_type(16)));

// ---------------------------------------------------------------------------
// Swizzled LDS layouts (chunk = 8 halfs = 16B, rotated by row).
// Per GROUP (4 waves): act 64x256 fp16 (32 KiB, in-place) + x 64x64 (8 KiB).
// Block = 2 groups = 81920 B -> 2 blocks/CU = 16 waves/CU.
// ---------------------------------------------------------------------------
__device__ __forceinline__ int swz(int row, int col) {
    return row * 256 + ((((col >> 3) + row) & 31) << 3) + (col & 7);
}
__device__ __forceinline__ int xswz(int row, int col) {
    return row * 64 + ((((col >> 3) + row) & 7) << 3) + (col & 7);
}

// ---------------------------------------------------------------------------
// Weight pre-pack (unchanged, proven R5-R11): fp32 (K,N) row-major -> fp16
// fragment order; lane L holds W[kt*16 + 8*(L>>5) + j][nt*32 + (L&31)].
// Fed to the MFMA *A* operand so D = C^T. K zero-padded: L1 39->64 (KT=4),
// L5 295->320 (KT=20), others 256 (KT=16). L9 N 4->32. Tile starts (1KB):
// {0,32,160,288,416,576,704,832,960}, total 976 tiles = 999424 B in d_ws.
// ---------------------------------------------------------------------------
__global__ void pack_w32(const float* __restrict__ w1, const float* __restrict__ w2,
                         const float* __restrict__ w3, const float* __restrict__ w4,
                         const float* __restrict__ w5, const float* __restrict__ w6,
                         const float* __restrict__ w7, const float* __restrict__ w8,
                         const float* __restrict__ w9, _Float16* __restrict__ dst) {
    const int tileStart[10] = {0, 32, 160, 288, 416, 576, 704, 832, 960, 976};
    const int Ks[9] = {39, 256, 256, 256, 295, 256, 256, 256, 256};
    const int Ns[9] = {256, 256, 256, 256, 256, 256, 256, 256, 4};
    const int Tn[9] = {8, 8, 8, 8, 8, 8, 8, 8, 1};
    const float* ws[9] = {w1, w2, w3, w4, w5, w6, w7, w8, w9};

    int g = blockIdx.x * blockDim.x + threadIdx.x;
    int tile = g >> 6, lane = g & 63;
    if (tile >= 976) return;
    int layer = 0;
    while (tile >= tileStart[layer + 1]) layer++;
    int t = tile - tileStart[layer];
    int tn = Tn[layer];
    int kt = t / tn, nt = t - kt * tn;
    int k0 = kt * 16 + (lane >> 5) * 8;
    int n = nt * 32 + (lane & 31);
    const float* w = ws[layer];
    int K = Ks[layer], N = Ns[layer];
    _Float16 v[8];
#pragma unroll
    for (int j = 0; j < 8; j++) {
        int k = k0 + j;
        v[j] = (k < K && n < N) ? (_Float16)w[k * N + n] : (_Float16)0.f;
    }
    *(half8*)(dst + (size_t)tile * 512 + lane * 8) = *(half8*)v;
}

// Act-fragment read (rows 0..31 -> a0, 32..63 -> a1); MFMA *B* operand.
// AMODE 0: act buffer. 1: ks>=KS0 from x buffer. 2: entirely x buffer.
template <int AMODE, int KS0>
__device__ __forceinline__ void loadA(const _Float16* abuf,
                                      const _Float16* __restrict__ xbuf,
                                      int ks, int l31, int lhi,
                                      half8& a0, half8& a1) {
    if (AMODE == 2 || (AMODE == 1 && ks >= KS0)) {
        int c = ((AMODE == 2) ? ks : (ks - KS0)) * 16 + lhi * 8;
        a0 = *(const half8*)(xbuf + xswz(l31, c));
        a1 = *(const half8*)(xbuf + xswz(32 + l31, c));
    } else {
        int c = ks * 16 + lhi * 8;
        a0 = *(const half8*)(abuf + swz(l31, c));
        a1 = *(const half8*)(abuf + swz(32 + l31, c));
    }
}

// ---------------------------------------------------------------------------
// R12: R10's proven layer body SPLIT into kpart (k-loop, MFMA-heavy) and
// epart (bias+relu+cvt+ds_write, VALU/LDS-heavy), with NO internal barriers.
// The kernel runs two 4-wave groups one phase apart so every barrier
// interval pairs one group's kpart with the other's epart — MFMA issue in
// every interval (R10's convoy left the MFMA pipe idle ~56% of the time).
// ---------------------------------------------------------------------------
template <int KT, int AMODE, int KS0>
__device__ __forceinline__ void kpart(const _Float16* abuf,
                                      const _Float16* __restrict__ xbuf,
                                      const half8* __restrict__ wq,
                                      int lane, int npair,
                                      floatx16& acc00, floatx16& acc10,
                                      floatx16& acc01, floatx16& acc11) {
    static_assert((KT & 1) == 0 && KT >= 4, "KT must be even >= 4");
    const int l31 = lane & 31, lhi = lane >> 5;
    const half8* wl = wq + (npair * 2) * 64 + lane;
    acc00 = {}; acc10 = {}; acc01 = {}; acc11 = {};
    half8 wA0 = wl[0], wA1 = wl[64];
    half8 wB0 = wl[512], wB1 = wl[512 + 64];
#pragma unroll 1
    for (int ks = 0; ks < KT - 2; ks += 2) {
        half8 nA0 = wl[(ks + 2) * 512], nA1 = wl[(ks + 2) * 512 + 64];
        half8 nB0 = wl[(ks + 3) * 512], nB1 = wl[(ks + 3) * 512 + 64];
        half8 a0, a1;
        loadA<AMODE, KS0>(abuf, xbuf, ks, l31, lhi, a0, a1);
        acc00 = __builtin_amdgcn_mfma_f32_32x32x16_f16(wA0, a0, acc00, 0, 0, 0);
        acc10 = __builtin_amdgcn_mfma_f32_32x32x16_f16(wA1, a0, acc10, 0, 0, 0);
        acc01 = __builtin_amdgcn_mfma_f32_32x32x16_f16(wA0, a1, acc01, 0, 0, 0);
        acc11 = __builtin_amdgcn_mfma_f32_32x32x16_f16(wA1, a1, acc11, 0, 0, 0);
        loadA<AMODE, KS0>(abuf, xbuf, ks + 1, l31, lhi, a0, a1);
        acc00 = __builtin_amdgcn_mfma_f32_32x32x16_f16(wB0, a0, acc00, 0, 0, 0);
        acc10 = __builtin_amdgcn_mfma_f32_32x32x16_f16(wB1, a0, acc10, 0, 0, 0);
        acc01 = __builtin_amdgcn_mfma_f32_32x32x16_f16(wB0, a1, acc01, 0, 0, 0);
        acc11 = __builtin_amdgcn_mfma_f32_32x32x16_f16(wB1, a1, acc11, 0, 0, 0);
        wA0 = nA0; wA1 = nA1; wB0 = nB0; wB1 = nB1;
    }
    {   // tail: k-steps KT-2 (wA) and KT-1 (wB), already in the ring
        half8 a0, a1;
        loadA<AMODE, KS0>(abuf, xbuf, KT - 2, l31, lhi, a0, a1);
        acc00 = __builtin_amdgcn_mfma_f32_32x32x16_f16(wA0, a0, acc00, 0, 0, 0);
        acc10 = __builtin_amdgcn_mfma_f32_32x32x16_f16(wA1, a0, acc10, 0, 0, 0);
        acc01 = __builtin_amdgcn_mfma_f32_32x32x16_f16(wA0, a1, acc01, 0, 0, 0);
        acc11 = __builtin_amdgcn_mfma_f32_32x32x16_f16(wA1, a1, acc11, 0, 0, 0);
        loadA<AMODE, KS0>(abuf, xbuf, KT - 1, l31, lhi, a0, a1);
        acc00 = __builtin_amdgcn_mfma_f32_32x32x16_f16(wB0, a0, acc00, 0, 0, 0);
        acc10 = __builtin_amdgcn_mfma_f32_32x32x16_f16(wB1, a0, acc10, 0, 0, 0);
        acc01 = __builtin_amdgcn_mfma_f32_32x32x16_f16(wB0, a1, acc01, 0, 0, 0);
        acc11 = __builtin_amdgcn_mfma_f32_32x32x16_f16(wB1, a1, acc11, 0, 0, 0);
    }
}

__device__ __forceinline__ void epart(const floatx16& acc00, const floatx16& acc10,
                                      const floatx16& acc01, const floatx16& acc11,
                                      const float* __restrict__ bias,
                                      _Float16* obuf, int lane, int npair) {
    const int l31 = lane & 31, lhi = lane >> 5;
    // Anti-hoist fence: bias loads stay out of the k-loop live range (R8-R10).
    asm volatile("" ::: "memory");
    floatx4 bv[2][4];
#pragma unroll
    for (int ni = 0; ni < 2; ni++)
#pragma unroll
        for (int g = 0; g < 4; g++)
            bv[ni][g] = *(const floatx4*)(bias + npair * 64 + ni * 32 + lhi * 4 + g * 8);
    // D=C^T: row m = mi*32 + l31, col n = npair*64 + ni*32 + lhi*4 + g*8 + r.
#pragma unroll
    for (int ni = 0; ni < 2; ni++) {
#pragma unroll
        for (int mi = 0; mi < 2; mi++) {
            const floatx16 accv = (ni == 0) ? (mi == 0 ? acc00 : acc01)
                                            : (mi == 0 ? acc10 : acc11);
            int row = mi * 32 + l31;
#pragma unroll
            for (int g = 0; g < 4; g++) {
                int col = npair * 64 + ni * 32 + lhi * 4 + g * 8;
                half4v h;
#pragma unroll
                for (int r = 0; r < 4; r++) {
                    float v = accv[g * 4 + r] + bv[ni][g][r];
                    v = v > 0.f ? v : 0.f;
                    h[r] = (_Float16)v;
                }
                *(half4v*)(obuf + swz(row, col)) = h;
            }
        }
    }
}

// Layer 9 split: 256 -> 4 (N padded to 32). Waves 0,1 of the group take one
// 32-row m-tile each; D[n][m]: lanes 0..31 hold n=r (r<4) for row m=l31.
__device__ __forceinline__ void k9part(const _Float16* abuf,
                                       const half8* __restrict__ wq,
                                       int lane, int w4, floatx16& acc) {
    if (w4 >= 2) return;
    const int l31 = lane & 31, lhi = lane >> 5;
    acc = {};
    const half8* wl = wq + lane;
    half8 wc = wl[0];
#pragma unroll 1
    for (int ks = 0; ks < 15; ks++) {
        half8 wn = wl[(ks + 1) * 64];
        half8 a = *(const half8*)(abuf + swz(w4 * 32 + l31, ks * 16 + lhi * 8));
        acc = __builtin_amdgcn_mfma_f32_32x32x16_f16(wc, a, acc, 0, 0, 0);
        wc = wn;
    }
    half8 a = *(const half8*)(abuf + swz(w4 * 32 + l31, 15 * 16 + lhi * 8));
    acc = __builtin_amdgcn_mfma_f32_32x32x16_f16(wc, a, acc, 0, 0, 0);
}

__device__ __forceinline__ void e9part(const floatx16& acc,
                                       const float* __restrict__ b9,
                                       float* __restrict__ out, long r0,
                                       int lane, int w4) {
    if (w4 >= 2) return;
    const int l31 = lane & 31, lhi = lane >> 5;
    if (lhi == 0) {
        asm volatile("" ::: "memory");
        floatx4 b4 = *(const floatx4*)(b9);
        floatx4 o;
#pragma unroll
        for (int r = 0; r < 4; r++) o[r] = acc[r] + b4[r];
        *(floatx4*)(out + (r0 + w4 * 32 + l31) * 4) = o;
    }
}

__global__ __launch_bounds__(512, 4) void mlp_fused(
    const float* __restrict__ x, const _Float16* __restrict__ wpk,
    const float* __restrict__ b1, const float* __restrict__ b2,
    const float* __restrict__ b3, const float* __restrict__ b4,
    const float* __restrict__ b5, const float* __restrict__ b6,
    const float* __restrict__ b7, const float* __restrict__ b8,
    const float* __restrict__ b9, float* __restrict__ out) {
    // Two groups x (32 KiB act + 8 KiB x) = 81920 B -> 2 blocks/CU,
    // 16 waves/CU = 4 waves/SIMD at <=128 total regs/wave (R10 body).
    __shared__ _Float16 lds[2 * (64 * 256 + 64 * 64)];
    const int tid = threadIdx.x;
    const int lane = tid & 63, wave = tid >> 6;
    const int grp = wave >> 2;            // 0 or 1: which 64-row tile
    const int w4 = wave & 3;              // n-pair within group
    _Float16* buf = lds + grp * (64 * 256 + 64 * 64);
    _Float16* xbuf = buf + 64 * 256;
    const long r0 = (long)blockIdx.x * 128 + grp * 64;

    // Stage this group's x tile (group-private 256 threads).
    const int tidg = tid & 255;
    for (int i = tidg; i < 64 * 25; i += 256) {
        int row = i / 25, col = 39 + (i - row * 25);
        xbuf[xswz(row, col)] = (_Float16)0.f;
    }
    for (int i = tidg; i < 64 * 39; i += 256) {
        int row = i / 39, col = i - row * 39;
        xbuf[xswz(row, col)] = (_Float16)x[r0 * 39 + i];
    }
    __syncthreads();

    const half8* wp = (const half8*)wpk;  // tile = 64 half8 (1 KB)
    const half8* w1q = wp + (size_t)0 * 64;
    const half8* w2q = wp + (size_t)32 * 64;
    const half8* w3q = wp + (size_t)160 * 64;
    const half8* w4q = wp + (size_t)288 * 64;
    const half8* w5q = wp + (size_t)416 * 64;
    const half8* w6q = wp + (size_t)576 * 64;
    const half8* w7q = wp + (size_t)704 * 64;
    const half8* w8q = wp + (size_t)832 * 64;
    const half8* w9q = wp + (size_t)960 * 64;

    floatx16 a00, a10, a01, a11;

    auto K1 = [&] { kpart<4, 2, 0>(xbuf, xbuf, w1q, lane, w4, a00, a10, a01, a11); };
    auto E1 = [&] { epart(a00, a10, a01, a11, b1, buf, lane, w4); };
    auto K2 = [&] { kpart<16, 0, 0>(buf, xbuf, w2q, lane, w4, a00, a10, a01, a11); };
    auto E2 = [&] { epart(a00, a10, a01, a11, b2, buf, lane, w4); };
    auto K3 = [&] { kpart<16, 0, 0>(buf, xbuf, w3q, lane, w4, a00, a10, a01, a11); };
    auto E3 = [&] { epart(a00, a10, a01, a11, b3, buf, lane, w4); };
    auto K4 = [&] { kpart<16, 0, 0>(buf, xbuf, w4q, lane, w4, a00, a10, a01, a11); };
    auto E4 = [&] { epart(a00, a10, a01, a11, b4, buf, lane, w4); };
    auto K5 = [&] { kpart<20, 1, 16>(buf, xbuf, w5q, lane, w4, a00, a10, a01, a11); };
    auto E5 = [&] { epart(a00, a10, a01, a11, b5, buf, lane, w4); };
    auto K6 = [&] { kpart<16, 0, 0>(buf, xbuf, w6q, lane, w4, a00, a10, a01, a11); };
    auto E6 = [&] { epart(a00, a10, a01, a11, b6, buf, lane, w4); };
    auto K7 = [&] { kpart<16, 0, 0>(buf, xbuf, w7q, lane, w4, a00, a10, a01, a11); };
    auto E7 = [&] { epart(a00, a10, a01, a11, b7, buf, lane, w4); };
    auto K8 = [&] { kpart<16, 0, 0>(buf, xbuf, w8q, lane, w4, a00, a10, a01, a11); };
    auto E8 = [&] { epart(a00, a10, a01, a11, b8, buf, lane, w4); };
    auto K9 = [&] { k9part(buf, w9q, lane, w4, a00); };
    auto E9 = [&] { e9part(a00, b9, out, r0, lane, w4); };

    // Software pipeline: group 1 runs one phase behind group 0, so every
    // barrier interval pairs a kpart (MFMA) with an epart (VALU/LDS-write).
    if (grp == 0) K1();            __syncthreads();
    if (grp == 0) E1(); else K1(); __syncthreads();
    if (grp == 0) K2(); else E1(); __syncthreads();
    if (grp == 0) E2(); else K2(); __syncthreads();
    if (grp == 0) K3(); else E2(); __syncthreads();
    if (grp == 0) E3(); else K3(); __syncthreads();
    if (grp == 0) K4(); else E3(); __syncthreads();
    if (grp == 0) E4(); else K4(); __syncthreads();
    if (grp == 0) K5(); else E4(); __syncthreads();
    if (grp == 0) E5(); else K5(); __syncthreads();
    if (grp == 0) K6(); else E5(); __syncthreads();
    if (grp == 0) E6(); else K6(); __syncthreads();
    if (grp == 0) K7(); else E6(); __syncthreads();
    if (grp == 0) E7(); else K7(); __syncthreads();
    if (grp == 0) K8(); else E7(); __syncthreads();
    if (grp == 0) E8(); else K8(); __syncthreads();
    if (grp == 0) K9(); else E8(); __syncthreads();
    if (grp == 0) E9(); else K9(); __syncthreads();
    if (grp == 1) E9();
}

extern "C" void kernel_launch(void* const* d_in, const int* in_sizes, int n_in,
                              void* d_out, int out_size, void* d_ws, size_t ws_size,
                              hipStream_t stream) {
    const float* x = (const float*)d_in[0];
    const float* w[9];
    const float* b[9];
    for (int i = 0; i < 9; i++) {
        w[i] = (const float*)d_in[1 + 2 * i];
        b[i] = (const float*)d_in[2 + 2 * i];
    }
    _Float16* wpk = (_Float16*)d_ws;  // 999424 B

    pack_w32<<<244, 256, 0, stream>>>(w[0], w[1], w[2], w[3], w[4], w[5], w[6], w[7], w[8], wpk);
    mlp_fused<<<262144 / 128, 512, 0, stream>>>(x, wpk, b[0], b[1], b[2], b[3], b[4],
                                                b[5], b[6], b[7], b[8], (float*)d_out);
}

// Round 13
// 374.933 us; speedup vs baseline: 1.0477x; 1.0219x over previous
//
#include <hip/hip_runtime.h>
#include <hip/hip_bf16.h>

typedef _Float16 half8 __attribute__((ext_vector_type(8)));
typedef _Float16 half4v __attribute__((ext_vector_type(4)));
typedef float floatx4 __attribute__((ext_vector_type(4)));
typedef float floatx16 __attribute__((ext_vector_type(16)));

// ---------------------------------------------------------------------------
// Swizzled LDS layouts (chunk = 8 halfs = 16B, rotated by row).
// act buffer: 64x256 fp16 (32 KiB, single, in-place read->barrier->write).
// x buffer: 64x64 fp16 (8 KiB). Total 40960 B -> 4 blocks/CU.
// ---------------------------------------------------------------------------
__device__ __forceinline__ int swz(int row, int col) {
    return row * 256 + ((((col >> 3) + row) & 31) << 3) + (col & 7);
}
__device__ __forceinline__ int xswz(int row, int col) {
    return row * 64 + ((((col >> 3) + row) & 7) << 3) + (col & 7);
}

// ---------------------------------------------------------------------------
// Weight pre-pack (unchanged, proven R5-R12): fp32 (K,N) row-major -> fp16
// fragment order; lane L holds W[kt*16 + 8*(L>>5) + j][nt*32 + (L&31)].
// Fed to the MFMA *A* operand so D = C^T. K zero-padded: L1 39->64 (KT=4),
// L5 295->320 (KT=20), others 256 (KT=16). L9 N 4->32. Tile starts (1KB):
// {0,32,160,288,416,576,704,832,960}, total 976 tiles = 999424 B in d_ws.
// ---------------------------------------------------------------------------
__global__ void pack_w32(const float* __restrict__ w1, const float* __restrict__ w2,
                         const float* __restrict__ w3, const float* __restrict__ w4,
                         const float* __restrict__ w5, const float* __restrict__ w6,
                         const float* __restrict__ w7, const float* __restrict__ w8,
                         const float* __restrict__ w9, _Float16* __restrict__ dst) {
    const int tileStart[10] = {0, 32, 160, 288, 416, 576, 704, 832, 960, 976};
    const int Ks[9] = {39, 256, 256, 256, 295, 256, 256, 256, 256};
    const int Ns[9] = {256, 256, 256, 256, 256, 256, 256, 256, 4};
    const int Tn[9] = {8, 8, 8, 8, 8, 8, 8, 8, 1};
    const float* ws[9] = {w1, w2, w3, w4, w5, w6, w7, w8, w9};

    int g = blockIdx.x * blockDim.x + threadIdx.x;
    int tile = g >> 6, lane = g & 63;
    if (tile >= 976) return;
    int layer = 0;
    while (tile >= tileStart[layer + 1]) layer++;
    int t = tile - tileStart[layer];
    int tn = Tn[layer];
    int kt = t / tn, nt = t - kt * tn;
    int k0 = kt * 16 + (lane >> 5) * 8;
    int n = nt * 32 + (lane & 31);
    const float* w = ws[layer];
    int K = Ks[layer], N = Ns[layer];
    _Float16 v[8];
#pragma unroll
    for (int j = 0; j < 8; j++) {
        int k = k0 + j;
        v[j] = (k < K && n < N) ? (_Float16)w[k * N + n] : (_Float16)0.f;
    }
    *(half8*)(dst + (size_t)tile * 512 + lane * 8) = *(half8*)v;
}

// Act-fragment read (rows 0..31 -> a0, 32..63 -> a1); MFMA *B* operand.
// AMODE 0: act buffer. 1: ks>=KS0 from x buffer. 2: entirely x buffer.
template <int AMODE, int KS0>
__device__ __forceinline__ void loadA(const _Float16* abuf,
                                      const _Float16* __restrict__ xbuf,
                                      int ks, int l31, int lhi,
                                      half8& a0, half8& a1) {
    if (AMODE == 2 || (AMODE == 1 && ks >= KS0)) {
        int c = ((AMODE == 2) ? ks : (ks - KS0)) * 16 + lhi * 8;
        a0 = *(const half8*)(xbuf + xswz(l31, c));
        a1 = *(const half8*)(xbuf + xswz(32 + l31, c));
    } else {
        int c = ks * 16 + lhi * 8;
        a0 = *(const half8*)(abuf + swz(l31, c));
        a1 = *(const half8*)(abuf + swz(32 + l31, c));
    }
}

// Two k-steps of MFMA using already-resident W fragments.
template <int AMODE, int KS0>
__device__ __forceinline__ void two_steps(const _Float16* abuf,
                                          const _Float16* __restrict__ xbuf,
                                          int ks, int l31, int lhi,
                                          half8 wa0, half8 wa1, half8 wb0, half8 wb1,
                                          floatx16& acc00, floatx16& acc10,
                                          floatx16& acc01, floatx16& acc11) {
    half8 a0, a1;
    loadA<AMODE, KS0>(abuf, xbuf, ks, l31, lhi, a0, a1);
    acc00 = __builtin_amdgcn_mfma_f32_32x32x16_f16(wa0, a0, acc00, 0, 0, 0);
    acc10 = __builtin_amdgcn_mfma_f32_32x32x16_f16(wa1, a0, acc10, 0, 0, 0);
    acc01 = __builtin_amdgcn_mfma_f32_32x32x16_f16(wa0, a1, acc01, 0, 0, 0);
    acc11 = __builtin_amdgcn_mfma_f32_32x32x16_f16(wa1, a1, acc11, 0, 0, 0);
    loadA<AMODE, KS0>(abuf, xbuf, ks + 1, l31, lhi, a0, a1);
    acc00 = __builtin_amdgcn_mfma_f32_32x32x16_f16(wb0, a0, acc00, 0, 0, 0);
    acc10 = __builtin_amdgcn_mfma_f32_32x32x16_f16(wb1, a0, acc10, 0, 0, 0);
    acc01 = __builtin_amdgcn_mfma_f32_32x32x16_f16(wb0, a1, acc01, 0, 0, 0);
    acc11 = __builtin_amdgcn_mfma_f32_32x32x16_f16(wb1, a1, acc11, 0, 0, 0);
}

// ---------------------------------------------------------------------------
// One fused layer: C(64x256) = relu(A(64xK) @ W + b), in-place LDS->LDS.
// R13 = R10 (2m x 2n swapped-operand tile, depth-2 W prefetch, b64 epilogue,
// 40KiB LDS, (256,4) -> 16 waves/CU) with two issue-count cuts (R12 showed
// MfmaUtil+VALUBusy ~95%: issue-bound, so remove instructions):
//   1. Bias folded into acc INIT (load bias float4s, init accs with them) —
//      deletes 64 v_add_f32/wave/layer and the anti-hoist hack entirely.
//   2. K-loop unrolled x2 (4 k-steps/iter) with explicit two-stage register
//      naming — deletes the 32 v_mov/iter ring rotation (256/wave/layer).
// ---------------------------------------------------------------------------
template <int KT, int AMODE, int KS0>
__device__ __forceinline__ void layerT(const _Float16* abuf,
                                       const _Float16* __restrict__ xbuf,
                                       const half8* __restrict__ wq,
                                       const float* __restrict__ bias,
                                       _Float16* obuf,
                                       int lane, int wave) {
    static_assert((KT & 3) == 0 && KT >= 4, "KT must be a multiple of 4");
    const int l31 = lane & 31, lhi = lane >> 5;
    // W frag (kstep ks, n-tile wave*2+n): wl[ks*512 + n*64]
    const half8* wl = wq + (wave * 2) * 64 + lane;
    // Bias -> acc init. acc[ni][mi] element g*4+r maps to output channel
    // n = wave*64 + ni*32 + lhi*4 + g*8 + r, so acc init = bv[ni][g][r]
    // (identical for both mi). Replaces zero-init + epilogue add.
    floatx16 ai0, ai1;
#pragma unroll
    for (int g = 0; g < 4; g++) {
        floatx4 b0 = *(const floatx4*)(bias + wave * 64 + lhi * 4 + g * 8);
        floatx4 b1 = *(const floatx4*)(bias + wave * 64 + 32 + lhi * 4 + g * 8);
#pragma unroll
        for (int r = 0; r < 4; r++) { ai0[g * 4 + r] = b0[r]; ai1[g * 4 + r] = b1[r]; }
    }
    floatx16 acc00 = ai0, acc01 = ai0, acc10 = ai1, acc11 = ai1;
    half8 w0a = wl[0], w0b = wl[64];
    half8 w1a = wl[512], w1b = wl[512 + 64];
#pragma unroll 1
    for (int ks = 0; ks < KT - 4; ks += 4) {
        half8 w2a = wl[(ks + 2) * 512], w2b = wl[(ks + 2) * 512 + 64];
        half8 w3a = wl[(ks + 3) * 512], w3b = wl[(ks + 3) * 512 + 64];
        two_steps<AMODE, KS0>(abuf, xbuf, ks, l31, lhi, w0a, w0b, w1a, w1b,
                              acc00, acc10, acc01, acc11);
        w0a = wl[(ks + 4) * 512]; w0b = wl[(ks + 4) * 512 + 64];
        w1a = wl[(ks + 5) * 512]; w1b = wl[(ks + 5) * 512 + 64];
        two_steps<AMODE, KS0>(abuf, xbuf, ks + 2, l31, lhi, w2a, w2b, w3a, w3b,
                              acc00, acc10, acc01, acc11);
    }
    {   // tail: last 4 k-steps (w0/w1 hold KT-4, KT-3)
        half8 w2a = wl[(KT - 2) * 512], w2b = wl[(KT - 2) * 512 + 64];
        half8 w3a = wl[(KT - 1) * 512], w3b = wl[(KT - 1) * 512 + 64];
        two_steps<AMODE, KS0>(abuf, xbuf, KT - 4, l31, lhi, w0a, w0b, w1a, w1b,
                              acc00, acc10, acc01, acc11);
        two_steps<AMODE, KS0>(abuf, xbuf, KT - 2, l31, lhi, w2a, w2b, w3a, w3b,
                              acc00, acc10, acc01, acc11);
    }
    // In-place safety barrier: all waves' act-reads complete before any write.
    if (AMODE != 2) __syncthreads();
    // Epilogue: relu + fp16 cvt + b64 writes (bias already in acc).
    // D=C^T: row m = mi*32 + l31, col n = wave*64 + ni*32 + lhi*4 + g*8 + r.
#pragma unroll
    for (int ni = 0; ni < 2; ni++) {
#pragma unroll
        for (int mi = 0; mi < 2; mi++) {
            const floatx16 accv = (ni == 0) ? (mi == 0 ? acc00 : acc01)
                                            : (mi == 0 ? acc10 : acc11);
            int row = mi * 32 + l31;
#pragma unroll
            for (int g = 0; g < 4; g++) {
                int col = wave * 64 + ni * 32 + lhi * 4 + g * 8;
                half4v h;
#pragma unroll
                for (int r = 0; r < 4; r++) {
                    float v = accv[g * 4 + r];
                    v = v > 0.f ? v : 0.f;
                    h[r] = (_Float16)v;
                }
                *(half4v*)(obuf + swz(row, col)) = h;
            }
        }
    }
}

// Layer 9 (swapped): 256 -> 4 (N padded to 32). Waves 0,1 take m-tiles;
// D[n][m]: lanes 0..31 hold n=r (r<4) for row m=l31 -> one float4 store/lane.
__device__ __forceinline__ void layer9T(const _Float16* abuf,
                                        const half8* __restrict__ wq,
                                        const float* __restrict__ b9,
                                        float* __restrict__ out, long r0,
                                        int lane, int wave) {
    if (wave >= 2) return;
    const int l31 = lane & 31, lhi = lane >> 5;
    floatx16 acc = {};
    const half8* wl = wq + lane;
    half8 wc = wl[0];
#pragma unroll 1
    for (int ks = 0; ks < 15; ks++) {
        half8 wn = wl[(ks + 1) * 64];
        half8 a = *(const half8*)(abuf + swz(wave * 32 + l31, ks * 16 + lhi * 8));
        acc = __builtin_amdgcn_mfma_f32_32x32x16_f16(wc, a, acc, 0, 0, 0);
        wc = wn;
    }
    {
        half8 a = *(const half8*)(abuf + swz(wave * 32 + l31, 15 * 16 + lhi * 8));
        acc = __builtin_amdgcn_mfma_f32_32x32x16_f16(wc, a, acc, 0, 0, 0);
    }
    if (lhi == 0) {
        asm volatile("" ::: "memory");
        floatx4 b4 = *(const floatx4*)(b9);
        floatx4 o;
#pragma unroll
        for (int r = 0; r < 4; r++) o[r] = acc[r] + b4[r];
        *(floatx4*)(out + (r0 + wave * 32 + l31) * 4) = o;
    }
}

__global__ __launch_bounds__(256, 4) void mlp_fused(
    const float* __restrict__ x, const _Float16* __restrict__ wpk,
    const float* __restrict__ b1, const float* __restrict__ b2,
    const float* __restrict__ b3, const float* __restrict__ b4,
    const float* __restrict__ b5, const float* __restrict__ b6,
    const float* __restrict__ b7, const float* __restrict__ b8,
    const float* __restrict__ b9, float* __restrict__ out) {
    // Single 32 KiB act buffer + 8 KiB x tile = 40960 B; 4-wave blocks;
    // 4 blocks/CU = 16 waves/CU = 4 waves/SIMD at <=128 total regs/wave.
    __shared__ _Float16 lds[64 * 256 + 64 * 64];
    _Float16* buf = lds;
    _Float16* xbuf = lds + 64 * 256;
    const int tid = threadIdx.x;
    const int lane = tid & 63, wave = tid >> 6;
    const long r0 = (long)blockIdx.x * 64;

    // Stage x: zero pad cols (39..63) and fill cols 0..38 — disjoint, one barrier.
    for (int i = tid; i < 64 * 25; i += 256) {
        int row = i / 25, col = 39 + (i - row * 25);
        xbuf[xswz(row, col)] = (_Float16)0.f;
    }
    for (int i = tid; i < 64 * 39; i += 256) {
        int row = i / 39, col = i - row * 39;
        xbuf[xswz(row, col)] = (_Float16)x[r0 * 39 + i];  // contiguous 2496 floats
    }
    __syncthreads();

    const half8* wp = (const half8*)wpk;  // tile = 64 half8 (1 KB)
    const half8* w1q = wp + (size_t)0 * 64;
    const half8* w2q = wp + (size_t)32 * 64;
    const half8* w3q = wp + (size_t)160 * 64;
    const half8* w4q = wp + (size_t)288 * 64;
    const half8* w5q = wp + (size_t)416 * 64;
    const half8* w6q = wp + (size_t)576 * 64;
    const half8* w7q = wp + (size_t)704 * 64;
    const half8* w8q = wp + (size_t)832 * 64;
    const half8* w9q = wp + (size_t)960 * 64;

    layerT<4, 2, 0>(xbuf, xbuf, w1q, b1, buf, lane, wave);   // x -> buf
    __syncthreads();
    layerT<16, 0, 0>(buf, xbuf, w2q, b2, buf, lane, wave);
    __syncthreads();
    layerT<16, 0, 0>(buf, xbuf, w3q, b3, buf, lane, wave);
    __syncthreads();
    layerT<16, 0, 0>(buf, xbuf, w4q, b4, buf, lane, wave);
    __syncthreads();
    layerT<20, 1, 16>(buf, xbuf, w5q, b5, buf, lane, wave);  // [h|x] skip
    __syncthreads();
    layerT<16, 0, 0>(buf, xbuf, w6q, b6, buf, lane, wave);
    __syncthreads();
    layerT<16, 0, 0>(buf, xbuf, w7q, b7, buf, lane, wave);
    __syncthreads();
    layerT<16, 0, 0>(buf, xbuf, w8q, b8, buf, lane, wave);
    __syncthreads();
    layer9T(buf, w9q, b9, out, r0, lane, wave);
}

extern "C" void kernel_launch(void* const* d_in, const int* in_sizes, int n_in,
                              void* d_out, int out_size, void* d_ws, size_t ws_size,
                              hipStream_t stream) {
    const float* x = (const float*)d_in[0];
    const float* w[9];
    const float* b[9];
    for (int i = 0; i < 9; i++) {
        w[i] = (const float*)d_in[1 + 2 * i];
        b[i] = (const float*)d_in[2 + 2 * i];
    }
    _Float16* wpk = (_Float16*)d_ws;  // 999424 B

    pack_w32<<<244, 256, 0, stream>>>(w[0], w[1], w[2], w[3], w[4], w[5], w[6], w[7], w[8], wpk);
    mlp_fused<<<262144 / 64, 256, 0, stream>>>(x, wpk, b[0], b[1], b[2], b[3], b[4],
                                               b[5], b[6], b[7], b[8], (float*)d_out);
}